// Round 1
// baseline (1116.252 us; speedup 1.0000x reference)
//
#include <hip/hip_runtime.h>

// ======================================================================
// Involution net: 3 x (1x1 conv + dynamic-kernel apply w/ batch BN) + FC
// B=1024. All fp32 (no fp32 MFMA on CDNA4 -> vector ALU).
//
// Per layer:
//   P1: per-image GEMM y=[W_init;W_red]@x (K-chunked LDS staging, 8xTN
//       register tile). Epilogue writes xi (full res), avgpools the red
//       half via shfl, writes r_pre, atomically accumulates BN sum/sumsq.
//   P3: per-image: scale/shift from stats (redundant per block, trivial),
//       r=relu(BN(r_pre)) in LDS, kern=W_span@r in LDS, patch-apply from
//       xi (float2 loads for k=2/s=2; LDS-staged xi for k=3/s=1/p=1).
// FC: per-image 4096->16 with wave shfl reduce.
// ======================================================================

// ---------------- workspace layout (floats) ----------------
// wcatT1 [200][128], wcatT2 [64][256], wcatT3 [128][512]
// stats: sum/sumsq per layer (zeroed via hipMemsetAsync each launch)
// xi arena (max 64*256 per img), rpre arena (max 4096 per img),
// out1/out2/out3 arenas.   Total ~120.4 MiB.
static constexpr size_t OFF_WCAT1 = 0;
static constexpr size_t OFF_WCAT2 = 25600;
static constexpr size_t OFF_WCAT3 = 41984;
static constexpr size_t OFF_SUM1  = 107520;
static constexpr size_t OFF_SQS1  = 107584;
static constexpr size_t OFF_SUM2  = 107648;
static constexpr size_t OFF_SQS2  = 107776;
static constexpr size_t OFF_SUM3  = 107904;
static constexpr size_t OFF_SQS3  = 108160;
static constexpr size_t OFF_XI    = 108416;     // 16777216 floats
static constexpr size_t OFF_RPRE  = 16885632;   //  4194304
static constexpr size_t OFF_OUT1  = 21079936;   //  4194304
static constexpr size_t OFF_OUT2  = 25274240;   //  2097152
static constexpr size_t OFF_OUT3  = 27371392;   //  4194304 -> 31565696 total

// ---------------- weight concat+transpose prep ----------------
// wcatT[c][m] = m<cout ? W_init[m][c] : W_red[m-cout][c]
__global__ void prep_wcat(const float* __restrict__ wi,
                          const float* __restrict__ wr,
                          float* __restrict__ wt, int cin, int cout) {
    int e = blockIdx.x * 256 + threadIdx.x;
    int M = 2 * cout;
    if (e >= cin * M) return;
    int c = e / M, m = e % M;
    wt[e] = (m < cout) ? wi[m * cin + c] : wr[(m - cout) * cin + c];
}

// ---------------- P1 ----------------
template<int CIN, int COUT, int H, int W, int S>
__global__ __launch_bounds__(256) void p1_kernel(
    const float* __restrict__ x,     // [B][CIN][H*W]
    const float* __restrict__ wcatT, // [CIN][2*COUT]
    float* __restrict__ xi,          // [B][COUT][H*W]
    float* __restrict__ rpre,        // [B][COUT][NQ]
    float* __restrict__ stat_sum,    // [COUT]
    float* __restrict__ stat_sqs)    // [COUT]
{
    constexpr int N  = H * W;
    constexpr int M  = 2 * COUT;
    constexpr int NT = H;            // threads along N (thread owns row tn)
    constexpr int TN = W;            // cols per thread
    constexpr int MT = 256 / NT;
    constexpr int TM = M / MT;
    static_assert(TM == 8, "tiling assumes 8 rows/thread");
    static_assert(TN % 4 == 0 && N % 4 == 0 && M % 4 == 0, "");
    constexpr int KC = 16;
    constexpr int HO = (S == 2) ? H / 2 : H;
    constexpr int WO = (S == 2) ? W / 2 : W;
    constexpr int NQ = HO * WO;

    __shared__ float Xs[KC * N];
    __shared__ float Ws[KC * M];

    const int tid = threadIdx.x;
    const int tn  = tid % NT;
    const int tm  = tid / NT;
    const int b   = blockIdx.x;

    const float* xb = x + (size_t)b * CIN * N;

    float acc[TM][TN];
    #pragma unroll
    for (int i = 0; i < TM; ++i)
        #pragma unroll
        for (int j = 0; j < TN; ++j) acc[i][j] = 0.f;

    for (int c0 = 0; c0 < CIN; c0 += KC) {
        const int kc = (CIN - c0 < KC) ? (CIN - c0) : KC;
        // stage X chunk [kc][N] (x[b] rows contiguous -> linear copy)
        for (int e = tid * 4; e < kc * N; e += 1024)
            *(float4*)(Xs + e) = *(const float4*)(xb + (size_t)c0 * N + e);
        // stage W chunk [kc][M]
        for (int e = tid * 4; e < kc * M; e += 1024)
            *(float4*)(Ws + e) = *(const float4*)(wcatT + (size_t)c0 * M + e);
        __syncthreads();
        for (int c = 0; c < kc; ++c) {
            float xf[TN], wf[TM];
            #pragma unroll
            for (int j = 0; j < TN; j += 4) {
                float4 v = *(const float4*)(Xs + c * N + tn * TN + j);
                xf[j] = v.x; xf[j + 1] = v.y; xf[j + 2] = v.z; xf[j + 3] = v.w;
            }
            #pragma unroll
            for (int i = 0; i < TM; i += 4) {
                float4 v = *(const float4*)(Ws + c * M + tm * TM + i);
                wf[i] = v.x; wf[i + 1] = v.y; wf[i + 2] = v.z; wf[i + 3] = v.w;
            }
            #pragma unroll
            for (int i = 0; i < TM; ++i)
                #pragma unroll
                for (int j = 0; j < TN; ++j)
                    acc[i][j] = fmaf(wf[i], xf[j], acc[i][j]);
        }
        __syncthreads();
    }

    const int gm0 = tm * TM;
    if (gm0 < COUT) {
        // xi rows: thread (tm,tn) holds rows gm0..gm0+7, cols tn*TN..+TN
        #pragma unroll
        for (int i = 0; i < TM; ++i) {
            float* dst = xi + ((size_t)b * COUT + gm0 + i) * N + tn * TN;
            #pragma unroll
            for (int j = 0; j < TN; j += 4) {
                float4 v;
                v.x = acc[i][j]; v.y = acc[i][j + 1];
                v.z = acc[i][j + 2]; v.w = acc[i][j + 3];
                *(float4*)(dst + j) = v;
            }
        }
    } else {
        // red rows -> avgpool (S==2) or passthrough (S==1), + BN stats
        const float sfac = (S == 2) ? 0.5f : 1.0f;  // pair-duplication fix
        #pragma unroll
        for (int i = 0; i < TM; ++i) {
            const int mr = gm0 + i - COUT;
            float s1 = 0.f, s2 = 0.f;
            if (S == 2) {
                float rq[WO];
                #pragma unroll
                for (int j2 = 0; j2 < WO; ++j2) {
                    float hp = acc[i][2 * j2] + acc[i][2 * j2 + 1];
                    float vp = hp + __shfl_xor(hp, 1);   // rows tn, tn^1
                    rq[j2] = 0.25f * vp;
                    s1 += rq[j2]; s2 += rq[j2] * rq[j2];
                }
                if ((tn & 1) == 0) {
                    float* dst = rpre + ((size_t)b * COUT + mr) * NQ + (tn >> 1) * WO;
                    #pragma unroll
                    for (int j2 = 0; j2 < WO; j2 += 4) {
                        float4 v;
                        v.x = rq[j2]; v.y = rq[j2 + 1];
                        v.z = rq[j2 + 2]; v.w = rq[j2 + 3];
                        *(float4*)(dst + j2) = v;
                    }
                }
            } else {
                float* dst = rpre + ((size_t)b * COUT + mr) * NQ + tn * W;
                #pragma unroll
                for (int j = 0; j < TN; j += 4) {
                    float4 v;
                    v.x = acc[i][j]; v.y = acc[i][j + 1];
                    v.z = acc[i][j + 2]; v.w = acc[i][j + 3];
                    *(float4*)(dst + j) = v;
                    s1 += acc[i][j] + acc[i][j + 1] + acc[i][j + 2] + acc[i][j + 3];
                    s2 += acc[i][j] * acc[i][j] + acc[i][j + 1] * acc[i][j + 1]
                        + acc[i][j + 2] * acc[i][j + 2] + acc[i][j + 3] * acc[i][j + 3];
                }
            }
            // reduce over the NT lanes sharing this tm group
            #pragma unroll
            for (int off = 1; off < NT; off <<= 1) {
                s1 += __shfl_xor(s1, off);
                s2 += __shfl_xor(s2, off);
            }
            if (tn == 0) {
                atomicAdd(stat_sum + mr, s1 * sfac);
                atomicAdd(stat_sqs + mr, s2 * sfac);
            }
        }
    }
}

// ---------------- P3 ----------------
template<int COUT, int H, int W, int K, int S, int PAD>
__global__ __launch_bounds__(256) void p3_kernel(
    const float* __restrict__ xi,    // [B][COUT][H*W]
    const float* __restrict__ rpre,  // [B][COUT][NQ]
    const float* __restrict__ ssum,
    const float* __restrict__ ssqs,
    const float* __restrict__ gamma,
    const float* __restrict__ beta,
    const float* __restrict__ wspan, // [K*K][COUT]
    float* __restrict__ out,         // [B][COUT][NQ]
    float inv_cnt)
{
    constexpr int HO = (S == 2) ? H / 2 : H;
    constexpr int WO = (S == 2) ? W / 2 : W;
    constexpr int NQ = HO * WO;
    constexpr int K2 = K * K;
    constexpr int N  = H * W;
    static_assert((S == 2 && K == 2 && PAD == 0) || (S == 1 && K == 3 && PAD == 1), "");

    __shared__ float sc[COUT], sh[COUT];
    __shared__ float rl[COUT * NQ];
    __shared__ float kl[K2 * NQ];
    __shared__ float xil[(S == 1) ? COUT * N : 4];

    const int tid = threadIdx.x;
    const int b   = blockIdx.x;

    for (int o = tid; o < COUT; o += 256) {
        float mean = ssum[o] * inv_cnt;
        float var  = ssqs[o] * inv_cnt - mean * mean;
        float s    = gamma[o] * rsqrtf(var + 1e-5f);
        sc[o] = s;
        sh[o] = beta[o] - mean * s;
    }
    __syncthreads();

    const float* rp = rpre + (size_t)b * COUT * NQ;
    for (int e = tid; e < COUT * NQ; e += 256) {
        int o = e / NQ;
        rl[e] = fmaxf(fmaf(sc[o], rp[e], sh[o]), 0.f);
    }
    const float* xb = xi + (size_t)b * COUT * N;
    if (S == 1) {
        for (int e = tid; e < COUT * N / 4; e += 256)
            ((float4*)xil)[e] = ((const float4*)xb)[e];
    }
    __syncthreads();

    // kern[kk][q] = sum_o wspan[kk][o] * r[o][q]
    for (int e = tid; e < K2 * NQ; e += 256) {
        int kk = e / NQ, q = e % NQ;
        float s = 0.f;
        for (int o = 0; o < COUT; ++o)
            s = fmaf(wspan[kk * COUT + o], rl[o * NQ + q], s);
        kl[e] = s;
    }
    __syncthreads();

    float* ob = out + (size_t)b * COUT * NQ;
    for (int e = tid; e < COUT * NQ; e += 256) {
        int o = e / NQ, q = e % NQ, ho = q / WO, wo = q % WO;
        float v;
        if (S == 2) {
            const float* p = xb + ((size_t)o * H + 2 * ho) * W + 2 * wo;
            float2 t  = *(const float2*)p;
            float2 bo = *(const float2*)(p + W);
            v = kl[0 * NQ + q] * t.x + kl[1 * NQ + q] * t.y
              + kl[2 * NQ + q] * bo.x + kl[3 * NQ + q] * bo.y;
        } else {
            v = 0.f;
            const float* xo = xil + o * N;
            #pragma unroll
            for (int ki = 0; ki < 3; ++ki) {
                int h = ho + ki - 1;
                if (h < 0 || h >= H) continue;
                #pragma unroll
                for (int kj = 0; kj < 3; ++kj) {
                    int w = wo + kj - 1;
                    if (w < 0 || w >= W) continue;
                    v = fmaf(kl[(ki * 3 + kj) * NQ + q], xo[h * W + w], v);
                }
            }
        }
        ob[e] = v;
    }
}

// ---------------- FC ----------------
__global__ __launch_bounds__(256) void fc_kernel(
    const float* __restrict__ h,    // [B][4096]
    const float* __restrict__ wfc,  // [16][4096]
    const float* __restrict__ bfc,  // [16]
    float* __restrict__ out)        // [B][16]
{
    __shared__ float hl[4096];
    __shared__ float red[4][16];
    const int tid = threadIdx.x, b = blockIdx.x;
    const float* hb = h + (size_t)b * 4096;
    for (int e = tid; e < 1024; e += 256)
        ((float4*)hl)[e] = ((const float4*)hb)[e];
    __syncthreads();
    float acc[16];
    #pragma unroll
    for (int n = 0; n < 16; ++n) acc[n] = 0.f;
    for (int i = 0; i < 16; ++i) {
        int f = tid + i * 256;
        float hv = hl[f];
        #pragma unroll
        for (int n = 0; n < 16; ++n)
            acc[n] = fmaf(hv, wfc[n * 4096 + f], acc[n]);
    }
    #pragma unroll
    for (int n = 0; n < 16; ++n) {
        float v = acc[n];
        #pragma unroll
        for (int off = 1; off < 64; off <<= 1) v += __shfl_xor(v, off);
        acc[n] = v;
    }
    const int wave = tid >> 6, lane = tid & 63;
    if (lane == 0) {
        #pragma unroll
        for (int n = 0; n < 16; ++n) red[wave][n] = acc[n];
    }
    __syncthreads();
    if (tid < 16)
        out[(size_t)b * 16 + tid] =
            red[0][tid] + red[1][tid] + red[2][tid] + red[3][tid] + bfc[tid];
}

// ---------------- launch ----------------
extern "C" void kernel_launch(void* const* d_in, const int* in_sizes, int n_in,
                              void* d_out, int out_size, void* d_ws, size_t ws_size,
                              hipStream_t stream) {
    const float* x    = (const float*)d_in[0];
    const float* Wi1  = (const float*)d_in[1];
    const float* Wr1  = (const float*)d_in[2];
    const float* g1   = (const float*)d_in[3];
    const float* be1  = (const float*)d_in[4];
    const float* Wsp1 = (const float*)d_in[5];
    const float* Wi2  = (const float*)d_in[6];
    const float* Wr2  = (const float*)d_in[7];
    const float* g2   = (const float*)d_in[8];
    const float* be2  = (const float*)d_in[9];
    const float* Wsp2 = (const float*)d_in[10];
    const float* Wi3  = (const float*)d_in[11];
    const float* Wr3  = (const float*)d_in[12];
    const float* g3   = (const float*)d_in[13];
    const float* be3  = (const float*)d_in[14];
    const float* Wsp3 = (const float*)d_in[15];
    const float* Wfc  = (const float*)d_in[16];
    const float* bfc  = (const float*)d_in[17];
    float* out = (float*)d_out;
    float* ws  = (float*)d_ws;

    float* wcat1 = ws + OFF_WCAT1;
    float* wcat2 = ws + OFF_WCAT2;
    float* wcat3 = ws + OFF_WCAT3;
    float* sum1 = ws + OFF_SUM1; float* sqs1 = ws + OFF_SQS1;
    float* sum2 = ws + OFF_SUM2; float* sqs2 = ws + OFF_SQS2;
    float* sum3 = ws + OFF_SUM3; float* sqs3 = ws + OFF_SQS3;
    float* xiA  = ws + OFF_XI;
    float* rB   = ws + OFF_RPRE;
    float* out1 = ws + OFF_OUT1;
    float* out2 = ws + OFF_OUT2;
    float* out3 = ws + OFF_OUT3;

    // zero BN stat accumulators (ws is poisoned 0xAA before every launch)
    hipMemsetAsync(sum1, 0, 896 * sizeof(float), stream);

    prep_wcat<<<(200 * 128 + 255) / 256, 256, 0, stream>>>(Wi1, Wr1, wcat1, 200, 64);
    prep_wcat<<<(64 * 256 + 255) / 256, 256, 0, stream>>>(Wi2, Wr2, wcat2, 64, 128);
    prep_wcat<<<(128 * 512 + 255) / 256, 256, 0, stream>>>(Wi3, Wr3, wcat3, 128, 256);

    // layer 1: 200->64, 16x16 -> 8x8
    p1_kernel<200, 64, 16, 16, 2><<<1024, 256, 0, stream>>>(x, wcat1, xiA, rB, sum1, sqs1);
    p3_kernel<64, 16, 16, 2, 2, 0><<<1024, 256, 0, stream>>>(
        xiA, rB, sum1, sqs1, g1, be1, Wsp1, out1, 1.f / (1024.f * 64.f));

    // layer 2: 64->128, 8x8 -> 4x4
    p1_kernel<64, 128, 8, 8, 2><<<1024, 256, 0, stream>>>(out1, wcat2, xiA, rB, sum2, sqs2);
    p3_kernel<128, 8, 8, 2, 2, 0><<<1024, 256, 0, stream>>>(
        xiA, rB, sum2, sqs2, g2, be2, Wsp2, out2, 1.f / (1024.f * 16.f));

    // layer 3: 128->256, 4x4 -> 4x4 (k=3,s=1,p=1)
    p1_kernel<128, 256, 4, 4, 1><<<1024, 256, 0, stream>>>(out2, wcat3, xiA, rB, sum3, sqs3);
    p3_kernel<256, 4, 4, 3, 1, 1><<<1024, 256, 0, stream>>>(
        xiA, rB, sum3, sqs3, g3, be3, Wsp3, out3, 1.f / (1024.f * 16.f));

    fc_kernel<<<1024, 256, 0, stream>>>(out3, Wfc, bfc, out);
}